// Round 8
// baseline (288.612 us; speedup 1.0000x reference)
//
#include <hip/hip_runtime.h>

// 2-layer GCN: coarse counting sort + per-coarse-bucket refine + LDS-local CSR
// + register aggregation, bf16 feature planes:
//   k_scatter: edges -> 1024-node COARSE buckets (334B segments: ~1.3x amp;
//              R7's 256-node segments at 84B gave 4.2x line-sharing amp)
//   k_refine:  per coarse bucket, wave-ballot partition into 4 fine 256-node
//              sub-buckets (dense same-block stores) + per-node degree -> dinv
//   k_emb:     ag1 = bf16(emb[x_ids]*dinv)  (3.2MB plane, L2-resident)
//   k_fuse1:   per fine bucket LDS CSR rebuild; 2 lanes/node register gather;
//              shfl halves; fused 16->32 GEMV+ReLU -> y1g (2 bf16 planes)
//   k_fuse2:   both planes in ONE kernel (lane = plane); register gather;
//              epilogue fuses graph pooling (sorted batch, <=2 graphs/bucket)
//              -> atomicAdd P[256][32]
//   k_final:   out[g] = P[g]@W2 + cnt[g]*b2
//
// Lessons: R1/R2 no scattered 4B stores / no hot global atomics; R4 no
// single-block stages; R6 LDS-atomic edge-parallel starved the machine ->
// register accumulation only; R7 fine-grained scatter segments share cache
// lines across XCDs -> sort coarse, refine locally.

constexpr int BLK = 256;
constexpr int EPB = 8192;          // edges per hist/scatter block
constexpr int CSH = 10;            // coarse: 1024 nodes per bucket
constexpr int CKN = 1 << CSH;
constexpr int BSH = 8;             // fine: 256 nodes per bucket
constexpr int BKTN = 1 << BSH;
constexpr int CAP = 10240;         // LDS edge-list capacity (chunked if over)

__device__ inline unsigned short f2bf(float x) {
  unsigned u = __float_as_uint(x);
  u += 0x7FFF + ((u >> 16) & 1);   // round-to-nearest-even
  return (unsigned short)(u >> 16);
}
__device__ inline float bf2f(unsigned short h) {
  return __uint_as_float((unsigned)h << 16);
}
__device__ inline unsigned pk(float a, float b) {
  return (unsigned)f2bf(a) | ((unsigned)f2bf(b) << 16);
}

// per-block LDS histogram of coarse col buckets
__global__ __launch_bounds__(BLK) void k_hist(const int* __restrict__ col, int E,
                                              int nbkt, int nblk,
                                              int* __restrict__ hist) {
  __shared__ int h[128];
  int tid = threadIdx.x, blk = blockIdx.x;
  for (int i = tid; i < nbkt; i += BLK) h[i] = 0;
  __syncthreads();
  int e0 = blk * EPB, e1 = min(E, e0 + EPB);
  for (int e = e0 + tid; e < e1; e += BLK) atomicAdd(&h[col[e] >> CSH], 1);
  __syncthreads();
  for (int b = tid; b < nbkt; b += BLK) hist[b * nblk + blk] = h[b];
}

// multi-block scan, stage 1: block-local exclusive scan + block sums
__global__ __launch_bounds__(1024) void k_scan_a(const int* __restrict__ hist, int tot,
                                                 int* __restrict__ off,
                                                 int* __restrict__ bsums) {
  __shared__ int sd[1024];
  int tid = threadIdx.x;
  int i = blockIdx.x * 1024 + tid;
  int v = (i < tot) ? hist[i] : 0;
  sd[tid] = v;
  __syncthreads();
  for (int o = 1; o < 1024; o <<= 1) {
    int u = (tid >= o) ? sd[tid - o] : 0;
    __syncthreads();
    sd[tid] += u;
    __syncthreads();
  }
  if (i < tot) off[i] = sd[tid] - v;  // block-local exclusive
  if (tid == 1023) bsums[blockIdx.x] = sd[tid];
}

// stage 2: add prefix of block sums (tree-reduced); derive coarse bucket starts
__global__ __launch_bounds__(1024) void k_scan_c(int tot, int nblk, int nbkt, int E,
                                                 int nscan,
                                                 const int* __restrict__ bsums,
                                                 int* __restrict__ off,
                                                 int* __restrict__ bucket_off) {
  __shared__ int sd[1024];
  int tid = threadIdx.x, b = blockIdx.x;
  sd[tid] = (tid < b && tid < nscan) ? bsums[tid] : 0;
  __syncthreads();
  for (int o = 512; o >= 1; o >>= 1) {
    if (tid < o) sd[tid] += sd[tid + o];
    __syncthreads();
  }
  int sbase = sd[0];
  int i = b * 1024 + tid;
  if (i < tot) {
    int v = off[i] + sbase;
    off[i] = v;
    if (i % nblk == 0) bucket_off[i / nblk] = v;
  }
  if (i == 0) bucket_off[nbkt] = E;
}

// scatter packed edges into coarse-bucket-major segments (dense per block)
__global__ __launch_bounds__(BLK) void k_scatter(const int* __restrict__ row,
                                                 const int* __restrict__ col, int E,
                                                 int nbkt, int nblk,
                                                 const int* __restrict__ off,
                                                 int* __restrict__ staging) {
  __shared__ int base[128];
  __shared__ int cur[128];
  int tid = threadIdx.x, blk = blockIdx.x;
  for (int b = tid; b < nbkt; b += BLK) {
    base[b] = off[b * nblk + blk];
    cur[b] = 0;
  }
  __syncthreads();
  int e0 = blk * EPB, e1 = min(E, e0 + EPB);
  for (int e = e0 + tid; e < e1; e += BLK) {
    int c = col[e];
    int b = c >> CSH;
    int rk = atomicAdd(&cur[b], 1);
    staging[base[b] + rk] = (row[e] << CSH) | (c & (CKN - 1));
  }
}

// per coarse bucket: partition into 4 fine sub-buckets via wave ballots
// (stores dense, same block, time-local) + per-node degree -> dinv
__global__ __launch_bounds__(1024) void k_refine(const int* __restrict__ staging,
                                                 const int* __restrict__ bucket_off,
                                                 int N, int E,
                                                 int* __restrict__ staging2,
                                                 int* __restrict__ fine_off,
                                                 float* __restrict__ dinv) {
  __shared__ int cur[4];
  __shared__ int ndeg[CKN];
  int tid = threadIdx.x, cb = blockIdx.x;
  int lane = tid & 63, wv = tid >> 6;
  int beg = bucket_off[cb], end = bucket_off[cb + 1];
  ndeg[tid] = 0;
  if (tid < 4) cur[tid] = 0;
  __syncthreads();
  // pass 1: fine sub-bucket totals
  int c0 = 0, c1 = 0, c2 = 0, c3 = 0;
  for (int i0 = beg + wv * 64; i0 < end; i0 += 1024) {
    int i = i0 + lane;
    int sid = (i < end) ? ((staging[i] >> 8) & 3) : 4;
    unsigned long long m0 = __ballot(sid == 0);
    unsigned long long m1 = __ballot(sid == 1);
    unsigned long long m2 = __ballot(sid == 2);
    unsigned long long m3 = __ballot(sid == 3);
    c0 += __popcll(m0); c1 += __popcll(m1);
    c2 += __popcll(m2); c3 += __popcll(m3);
  }
  if (lane == 0) {
    atomicAdd(&cur[0], c0); atomicAdd(&cur[1], c1);
    atomicAdd(&cur[2], c2); atomicAdd(&cur[3], c3);
  }
  __syncthreads();
  if (tid == 0) {
    int b0 = beg, b1 = b0 + cur[0], b2 = b1 + cur[1], b3 = b2 + cur[2];
    fine_off[cb * 4 + 0] = b0; fine_off[cb * 4 + 1] = b1;
    fine_off[cb * 4 + 2] = b2; fine_off[cb * 4 + 3] = b3;
    fine_off[cb * 4 + 4] = b3 + cur[3];  // next coarse overwrites; last = E
    cur[0] = b0; cur[1] = b1; cur[2] = b2; cur[3] = b3;
  }
  __syncthreads();
  // pass 2: scatter to fine segments (wave-aggregated cursor reservation)
  for (int i0 = beg + wv * 64; i0 < end; i0 += 1024) {
    int i = i0 + lane;
    int p = (i < end) ? staging[i] : 0;
    int sid = (i < end) ? ((p >> 8) & 3) : 4;
    unsigned long long m0 = __ballot(sid == 0);
    unsigned long long m1 = __ballot(sid == 1);
    unsigned long long m2 = __ballot(sid == 2);
    unsigned long long m3 = __ballot(sid == 3);
    int b0 = 0, b1 = 0, b2 = 0, b3 = 0;
    if (lane == 0) {
      b0 = atomicAdd(&cur[0], __popcll(m0));
      b1 = atomicAdd(&cur[1], __popcll(m1));
      b2 = atomicAdd(&cur[2], __popcll(m2));
      b3 = atomicAdd(&cur[3], __popcll(m3));
    }
    b0 = __shfl(b0, 0); b1 = __shfl(b1, 0);
    b2 = __shfl(b2, 0); b3 = __shfl(b3, 0);
    if (i < end) {
      unsigned long long lm = (lane == 63) ? ~0ull >> 1
                                           : ((1ull << (lane + 1)) - 1) >> 1;
      lm = ((unsigned long long)1 << lane) - 1;
      unsigned long long ms = (sid == 0) ? m0 : (sid == 1) ? m1 : (sid == 2) ? m2 : m3;
      int gb = (sid == 0) ? b0 : (sid == 1) ? b1 : (sid == 2) ? b2 : b3;
      int rank = __popcll(ms & lm);
      int r = p >> CSH, lc = p & (CKN - 1);
      staging2[gb + rank] = (r << BSH) | (lc & (BKTN - 1));
      atomicAdd(&ndeg[lc], 1);
    }
  }
  __syncthreads();
  int node = (cb << CSH) + tid;
  if (node < N) dinv[node] = rsqrtf((float)(ndeg[tid] + 1));  // +1 self-loop
}

// ag1[n] = bf16(emb[x_ids[n]] * dinv[n])
__global__ __launch_bounds__(BLK) void k_emb(const int* __restrict__ x_ids,
                                             const float* __restrict__ emb,
                                             const float* __restrict__ dinv, int N,
                                             unsigned short* __restrict__ ag1) {
  int node = blockIdx.x * BLK + threadIdx.x;
  if (node >= N) return;
  float d = dinv[node];
  const float* er = emb + (size_t)x_ids[node] * 16;
  float4 e0 = *(const float4*)(er);
  float4 e1 = *(const float4*)(er + 4);
  float4 e2 = *(const float4*)(er + 8);
  float4 e3 = *(const float4*)(er + 12);
  uint4 o0, o1;
  o0.x = pk(e0.x * d, e0.y * d); o0.y = pk(e0.z * d, e0.w * d);
  o0.z = pk(e1.x * d, e1.y * d); o0.w = pk(e1.z * d, e1.w * d);
  o1.x = pk(e2.x * d, e2.y * d); o1.y = pk(e2.z * d, e2.w * d);
  o1.z = pk(e3.x * d, e3.y * d); o1.w = pk(e3.z * d, e3.w * d);
  *(uint4*)(ag1 + (size_t)node * 16) = o0;
  *(uint4*)(ag1 + (size_t)node * 16 + 8) = o1;
}

// layer 1: LDS CSR rebuild + register aggregation + fused GEMV/ReLU.
// 512 threads: 2 lanes/node (half = 8 features, uint4 gathers).
__global__ __launch_bounds__(512) void k_fuse1(const unsigned short* __restrict__ ag1,
                                               const int* __restrict__ staging2,
                                               const int* __restrict__ fine_off,
                                               const float* __restrict__ dinv,
                                               const float* __restrict__ W1,
                                               const float* __restrict__ b1, int N,
                                               unsigned short* __restrict__ y1g) {
  __shared__ int list[CAP];
  __shared__ int cnt[BKTN], sc[BKTN], lcur[BKTN];
  __shared__ float W[512];
  __shared__ float bb[32];
  int tid = threadIdx.x, b = blockIdx.x;
  W[tid] = W1[tid];
  if (tid < 32) bb[tid] = b1[tid];
  int nloc = tid >> 1, half = tid & 1;
  int node = (b << BSH) + nloc;
  float acc[8];
  if (node < N) {
    uint4 v = *(const uint4*)(ag1 + (size_t)node * 16 + half * 8);
    acc[0] = bf2f(v.x & 0xFFFF); acc[1] = bf2f(v.x >> 16);
    acc[2] = bf2f(v.y & 0xFFFF); acc[3] = bf2f(v.y >> 16);
    acc[4] = bf2f(v.z & 0xFFFF); acc[5] = bf2f(v.z >> 16);
    acc[6] = bf2f(v.w & 0xFFFF); acc[7] = bf2f(v.w >> 16);
  } else {
#pragma unroll
    for (int k = 0; k < 8; ++k) acc[k] = 0.f;
  }
  int beg = fine_off[b], end = fine_off[b + 1];
  for (int cbeg = beg; cbeg < end; cbeg += CAP) {
    int cend = min(end, cbeg + CAP);
    if (tid < BKTN) cnt[tid] = 0;
    __syncthreads();
    for (int i = cbeg + tid; i < cend; i += 512)
      atomicAdd(&cnt[staging2[i] & (BKTN - 1)], 1);
    __syncthreads();
    if (tid < BKTN) sc[tid] = cnt[tid];
    __syncthreads();
    for (int o = 1; o < BKTN; o <<= 1) {
      int u = (tid < BKTN && tid >= o) ? sc[tid - o] : 0;
      __syncthreads();
      if (tid < BKTN) sc[tid] += u;
      __syncthreads();
    }
    if (tid < BKTN) {
      int st = sc[tid] - cnt[tid];
      sc[tid] = st;
      lcur[tid] = st;
    }
    __syncthreads();
    for (int i = cbeg + tid; i < cend; i += 512) {
      int p = staging2[i];
      int pos = atomicAdd(&lcur[p & (BKTN - 1)], 1);
      list[pos] = p >> BSH;
    }
    __syncthreads();
    if (node < N) {
      int st = sc[nloc], dg = cnt[nloc];
      for (int j = 0; j < dg; ++j) {
        int r = list[st + j];
        uint4 v = *(const uint4*)(ag1 + (size_t)r * 16 + half * 8);
        acc[0] += bf2f(v.x & 0xFFFF); acc[1] += bf2f(v.x >> 16);
        acc[2] += bf2f(v.y & 0xFFFF); acc[3] += bf2f(v.y >> 16);
        acc[4] += bf2f(v.z & 0xFFFF); acc[5] += bf2f(v.z >> 16);
        acc[6] += bf2f(v.w & 0xFFFF); acc[7] += bf2f(v.w >> 16);
      }
    }
    __syncthreads();
  }
  if (node >= N) return;
  float d = dinv[node];
  float sx[8], xo[8];
#pragma unroll
  for (int k = 0; k < 8; ++k) sx[k] = acc[k] * d;
#pragma unroll
  for (int k = 0; k < 8; ++k) xo[k] = __shfl_xor(sx[k], 1);
  float x[16];
  if (half == 0) {
#pragma unroll
    for (int k = 0; k < 8; ++k) { x[k] = sx[k]; x[8 + k] = xo[k]; }
  } else {
#pragma unroll
    for (int k = 0; k < 8; ++k) { x[k] = xo[k]; x[8 + k] = sx[k]; }
  }
  int j0 = half * 16;
  float a[16];
#pragma unroll
  for (int j = 0; j < 16; ++j) a[j] = bb[j0 + j];
#pragma unroll
  for (int k = 0; k < 16; ++k) {
    float xv = x[k];
#pragma unroll
    for (int j = 0; j < 16; ++j) a[j] += xv * W[k * 32 + j0 + j];
  }
#pragma unroll
  for (int j = 0; j < 16; ++j) a[j] = fmaxf(a[j], 0.f) * d;
  uint4 o0 = {pk(a[0], a[1]), pk(a[2], a[3]), pk(a[4], a[5]), pk(a[6], a[7])};
  uint4 o1 = {pk(a[8], a[9]), pk(a[10], a[11]), pk(a[12], a[13]), pk(a[14], a[15])};
  unsigned short* yp = y1g + (size_t)half * N * 16 + (size_t)node * 16;
  *(uint4*)(yp) = o0;
  *(uint4*)(yp + 8) = o1;
}

// layer 2, BOTH planes (lane = plane): LDS CSR rebuild + register aggregation
// + fused sorted-batch graph pooling -> atomicAdd P[G][32]
__global__ __launch_bounds__(512) void k_fuse2(const unsigned short* __restrict__ y1g,
                                               const int* __restrict__ staging2,
                                               const int* __restrict__ fine_off,
                                               const float* __restrict__ dinv,
                                               const int* __restrict__ batch, int N,
                                               float* __restrict__ P) {
  __shared__ int list[CAP];
  __shared__ int cnt[BKTN], sc[BKTN], lcur[BKTN];
  __shared__ float pool[8 * 33];
  int tid = threadIdx.x, b = blockIdx.x;
  int nloc = tid >> 1, plane = tid & 1;
  int node = (b << BSH) + nloc;
  const unsigned short* yp = y1g + (size_t)plane * N * 16;
  float acc[16];
  if (node < N) {
    uint4 v0 = *(const uint4*)(yp + (size_t)node * 16);
    uint4 v1 = *(const uint4*)(yp + (size_t)node * 16 + 8);
    acc[0] = bf2f(v0.x & 0xFFFF); acc[1] = bf2f(v0.x >> 16);
    acc[2] = bf2f(v0.y & 0xFFFF); acc[3] = bf2f(v0.y >> 16);
    acc[4] = bf2f(v0.z & 0xFFFF); acc[5] = bf2f(v0.z >> 16);
    acc[6] = bf2f(v0.w & 0xFFFF); acc[7] = bf2f(v0.w >> 16);
    acc[8] = bf2f(v1.x & 0xFFFF); acc[9] = bf2f(v1.x >> 16);
    acc[10] = bf2f(v1.y & 0xFFFF); acc[11] = bf2f(v1.y >> 16);
    acc[12] = bf2f(v1.z & 0xFFFF); acc[13] = bf2f(v1.z >> 16);
    acc[14] = bf2f(v1.w & 0xFFFF); acc[15] = bf2f(v1.w >> 16);
  } else {
#pragma unroll
    for (int k = 0; k < 16; ++k) acc[k] = 0.f;
  }
  int beg = fine_off[b], end = fine_off[b + 1];
  for (int cbeg = beg; cbeg < end; cbeg += CAP) {
    int cend = min(end, cbeg + CAP);
    if (tid < BKTN) cnt[tid] = 0;
    __syncthreads();
    for (int i = cbeg + tid; i < cend; i += 512)
      atomicAdd(&cnt[staging2[i] & (BKTN - 1)], 1);
    __syncthreads();
    if (tid < BKTN) sc[tid] = cnt[tid];
    __syncthreads();
    for (int o = 1; o < BKTN; o <<= 1) {
      int u = (tid < BKTN && tid >= o) ? sc[tid - o] : 0;
      __syncthreads();
      if (tid < BKTN) sc[tid] += u;
      __syncthreads();
    }
    if (tid < BKTN) {
      int st = sc[tid] - cnt[tid];
      sc[tid] = st;
      lcur[tid] = st;
    }
    __syncthreads();
    for (int i = cbeg + tid; i < cend; i += 512) {
      int p = staging2[i];
      int pos = atomicAdd(&lcur[p & (BKTN - 1)], 1);
      list[pos] = p >> BSH;
    }
    __syncthreads();
    if (node < N) {
      int st = sc[nloc], dg = cnt[nloc];
      for (int j = 0; j < dg; ++j) {
        int r = list[st + j];
        uint4 v0 = *(const uint4*)(yp + (size_t)r * 16);
        uint4 v1 = *(const uint4*)(yp + (size_t)r * 16 + 8);
        acc[0] += bf2f(v0.x & 0xFFFF); acc[1] += bf2f(v0.x >> 16);
        acc[2] += bf2f(v0.y & 0xFFFF); acc[3] += bf2f(v0.y >> 16);
        acc[4] += bf2f(v0.z & 0xFFFF); acc[5] += bf2f(v0.z >> 16);
        acc[6] += bf2f(v0.w & 0xFFFF); acc[7] += bf2f(v0.w >> 16);
        acc[8] += bf2f(v1.x & 0xFFFF); acc[9] += bf2f(v1.x >> 16);
        acc[10] += bf2f(v1.y & 0xFFFF); acc[11] += bf2f(v1.y >> 16);
        acc[12] += bf2f(v1.z & 0xFFFF); acc[13] += bf2f(v1.z >> 16);
        acc[14] += bf2f(v1.w & 0xFFFF); acc[15] += bf2f(v1.w >> 16);
      }
    }
    __syncthreads();
  }
  int myg = -1;
  if (node < N) {
    float d = dinv[node];
#pragma unroll
    for (int k = 0; k < 16; ++k) acc[k] *= d;
    myg = batch[node];
  }
  int g0 = batch[b << BSH];
  int g1 = batch[min((b << BSH) + BKTN - 1, N - 1)];
  for (int clo = g0; clo <= g1; clo += 8) {
    for (int j = tid; j < 8 * 33; j += 512) pool[j] = 0.f;
    __syncthreads();
    if (myg >= clo && myg < clo + 8) {
      float* pp = pool + (myg - clo) * 33 + plane * 16;
#pragma unroll
      for (int k = 0; k < 16; ++k) atomicAdd(pp + k, acc[k]);
    }
    __syncthreads();
    int ng = min(8, g1 - clo + 1);
    for (int j = tid; j < ng * 32; j += 512)
      atomicAdd(&P[(size_t)(clo + (j >> 5)) * 32 + (j & 31)],
                pool[(j >> 5) * 33 + (j & 31)]);
    __syncthreads();
  }
}

// out[g] = P[g] @ W2 + cnt[g]*b2; cnt via binary search on sorted batch
__global__ __launch_bounds__(64) void k_final(const float* __restrict__ P,
                                              const int* __restrict__ batch, int N,
                                              const float* __restrict__ W2,
                                              const float* __restrict__ b2,
                                              float* __restrict__ out) {
  __shared__ float pr[32];
  __shared__ int se[2];
  int g = blockIdx.x, tid = threadIdx.x;
  if (tid < 2) {
    int v = g + tid;
    int lo = 0, hi = N;
    while (lo < hi) {
      int mid = (lo + hi) >> 1;
      if (batch[mid] < v) lo = mid + 1; else hi = mid;
    }
    se[tid] = lo;
  }
  if (tid < 32) pr[tid] = P[(size_t)g * 32 + tid];
  __syncthreads();
  if (tid < 41) {
    float o = (float)(se[1] - se[0]) * b2[tid];
#pragma unroll
    for (int k = 0; k < 32; ++k) o += pr[k] * W2[k * 41 + tid];
    out[(size_t)g * 41 + tid] = o;
  }
}

extern "C" void kernel_launch(void* const* d_in, const int* in_sizes, int n_in,
                              void* d_out, int out_size, void* d_ws, size_t ws_size,
                              hipStream_t stream) {
  const int* x_ids = (const int*)d_in[0];
  const int* edge_index = (const int*)d_in[1];
  const int* batch = (const int*)d_in[2];
  const float* emb = (const float*)d_in[3];
  const float* W1 = (const float*)d_in[4];
  const float* b1 = (const float*)d_in[5];
  const float* W2 = (const float*)d_in[6];
  const float* b2 = (const float*)d_in[7];
  float* out = (float*)d_out;

  const int N = in_sizes[0];
  const int E = in_sizes[1] / 2;
  const int G = out_size / 41;
  const int* row = edge_index;
  const int* col = edge_index + E;

  const int ncb = (N + CKN - 1) >> CSH;         // 98 coarse buckets
  const int nfb = (N + BKTN - 1) >> BSH;        // 391 fine buckets
  const int nblk = (E + EPB - 1) / EPB;         // 391
  const int tot = ncb * nblk;                   // ~38K
  const int nscan = (tot + 1023) >> 10;         // ~38

  char* ws = (char*)d_ws;
  size_t woff = 0;
  auto alloc = [&](size_t bytes) -> char* {
    char* p = ws + woff;
    woff += (bytes + 255) & ~(size_t)255;
    return p;
  };
  int* staging = (int*)alloc((size_t)E * 4);
  int* staging2 = (int*)alloc((size_t)E * 4);
  float* dinv = (float*)alloc((size_t)N * 4);
  unsigned short* ag1 = (unsigned short*)alloc((size_t)N * 16 * 2);
  unsigned short* y1g = (unsigned short*)alloc((size_t)N * 32 * 2);
  int* hist = (int*)alloc((size_t)tot * 4);
  int* off = (int*)alloc((size_t)tot * 4);
  int* bucket_off = (int*)alloc(((size_t)ncb + 2) * 4);
  int* fine_off = (int*)alloc(((size_t)ncb * 4 + 2) * 4);
  int* bsums = (int*)alloc((size_t)nscan * 4);
  float* P = (float*)alloc((size_t)G * 32 * 4);
  (void)ws_size; (void)n_in;

  hipMemsetAsync(P, 0, (size_t)G * 32 * 4, stream);

  k_hist<<<nblk, BLK, 0, stream>>>(col, E, ncb, nblk, hist);
  k_scan_a<<<nscan, 1024, 0, stream>>>(hist, tot, off, bsums);
  k_scan_c<<<nscan, 1024, 0, stream>>>(tot, nblk, ncb, E, nscan, bsums, off, bucket_off);
  k_scatter<<<nblk, BLK, 0, stream>>>(row, col, E, ncb, nblk, off, staging);
  k_refine<<<ncb, 1024, 0, stream>>>(staging, bucket_off, N, E, staging2, fine_off, dinv);
  k_emb<<<(N + BLK - 1) / BLK, BLK, 0, stream>>>(x_ids, emb, dinv, N, ag1);
  k_fuse1<<<nfb, 512, 0, stream>>>(ag1, staging2, fine_off, dinv, W1, b1, N, y1g);
  k_fuse2<<<nfb, 512, 0, stream>>>(y1g, staging2, fine_off, dinv, batch, N, P);
  k_final<<<G, 64, 0, stream>>>(P, batch, N, W2, b2, out);
}

// Round 9
// 255.140 us; speedup vs baseline: 1.1312x; 1.1312x over previous
//
#include <hip/hip_runtime.h>

// 2-layer GCN: one-pass counting sort to FINE buckets + LDS-local CSR +
// register aggregation, bf16 feature planes:
//   k_hist/k_scan: per-(fine bucket, scatter block) segment offsets
//   k_scatter: 98 blocks x 1024 thr, EPB=32768 -> 336B dense segments
//              (R7: 84B segments shared lines across XCDs -> 4.2x write amp;
//               336B was amp-free in R3/R5). Packed (row<<8 | col&255).
//   k_degprep: per fine bucket degree -> dinv; ag1 = bf16(emb[x_ids]*dinv)
//   k_fuse1:   per fine bucket LDS CSR rebuild; 2 lanes/node register gather
//              (uint4); shfl halves; fused 16->32 GEMV+ReLU -> y1g (2 planes)
//   k_fuse2 x2 (ONE PLANE each -- R8: merging planes doubled the gather set
//              past the 4MB per-XCD L2, FETCH 20->155MB): register gather +
//              fused sorted-batch pooling -> atomicAdd P[256][32]
//   k_final:   out[g] = P[g]@W2 + cnt[g]*b2
//
// Standing lessons: R1/R2 no scattered-4B global stores / no hot global
// atomics; R4 no single-block serial stages; R6 LDS-atomic edge-parallel
// starves the machine -> register accumulation only; R3/R8 every gather pass
// must fit one bf16 plane (3.2MB) in L2.

constexpr int EPB = 32768;         // edges per hist/scatter block
constexpr int BSH = 8;             // 256 nodes per fine bucket
constexpr int BKTN = 1 << BSH;
constexpr int CAP = 10240;         // LDS edge-list capacity (chunked if over)

__device__ inline unsigned short f2bf(float x) {
  unsigned u = __float_as_uint(x);
  u += 0x7FFF + ((u >> 16) & 1);   // round-to-nearest-even
  return (unsigned short)(u >> 16);
}
__device__ inline float bf2f(unsigned short h) {
  return __uint_as_float((unsigned)h << 16);
}
__device__ inline unsigned pk(float a, float b) {
  return (unsigned)f2bf(a) | ((unsigned)f2bf(b) << 16);
}

// per-block LDS histogram of fine col buckets
__global__ __launch_bounds__(1024) void k_hist(const int* __restrict__ col, int E,
                                               int nbkt, int nblk,
                                               int* __restrict__ hist) {
  __shared__ int h[512];
  int tid = threadIdx.x, blk = blockIdx.x;
  for (int i = tid; i < nbkt; i += 1024) h[i] = 0;
  __syncthreads();
  int e0 = blk * EPB, e1 = min(E, e0 + EPB);
  for (int e = e0 + tid; e < e1; e += 1024) atomicAdd(&h[col[e] >> BSH], 1);
  __syncthreads();
  for (int b = tid; b < nbkt; b += 1024) hist[b * nblk + blk] = h[b];
}

// multi-block scan, stage 1: block-local exclusive scan + block sums
__global__ __launch_bounds__(1024) void k_scan_a(const int* __restrict__ hist, int tot,
                                                 int* __restrict__ off,
                                                 int* __restrict__ bsums) {
  __shared__ int sd[1024];
  int tid = threadIdx.x;
  int i = blockIdx.x * 1024 + tid;
  int v = (i < tot) ? hist[i] : 0;
  sd[tid] = v;
  __syncthreads();
  for (int o = 1; o < 1024; o <<= 1) {
    int u = (tid >= o) ? sd[tid - o] : 0;
    __syncthreads();
    sd[tid] += u;
    __syncthreads();
  }
  if (i < tot) off[i] = sd[tid] - v;  // block-local exclusive
  if (tid == 1023) bsums[blockIdx.x] = sd[tid];
}

// stage 2: add prefix of block sums (tree-reduced); derive bucket starts
__global__ __launch_bounds__(1024) void k_scan_c(int tot, int nblk, int nbkt, int E,
                                                 int nscan,
                                                 const int* __restrict__ bsums,
                                                 int* __restrict__ off,
                                                 int* __restrict__ bucket_off) {
  __shared__ int sd[1024];
  int tid = threadIdx.x, b = blockIdx.x;
  sd[tid] = (tid < b && tid < nscan) ? bsums[tid] : 0;
  __syncthreads();
  for (int o = 512; o >= 1; o >>= 1) {
    if (tid < o) sd[tid] += sd[tid + o];
    __syncthreads();
  }
  int sbase = sd[0];
  int i = b * 1024 + tid;
  if (i < tot) {
    int v = off[i] + sbase;
    off[i] = v;
    if (i % nblk == 0) bucket_off[i / nblk] = v;
  }
  if (i == 0) bucket_off[nbkt] = E;
}

// scatter packed edges into fine-bucket-major segments (dense per block)
__global__ __launch_bounds__(1024) void k_scatter(const int* __restrict__ row,
                                                  const int* __restrict__ col, int E,
                                                  int nbkt, int nblk,
                                                  const int* __restrict__ off,
                                                  int* __restrict__ staging) {
  __shared__ int base[512];
  __shared__ int cur[512];
  int tid = threadIdx.x, blk = blockIdx.x;
  for (int b = tid; b < nbkt; b += 1024) {
    base[b] = off[b * nblk + blk];
    cur[b] = 0;
  }
  __syncthreads();
  int e0 = blk * EPB, e1 = min(E, e0 + EPB);
  for (int e = e0 + tid; e < e1; e += 1024) {
    int c = col[e];
    int b = c >> BSH;
    int rk = atomicAdd(&cur[b], 1);
    staging[base[b] + rk] = (row[e] << BSH) | (c & (BKTN - 1));
  }
}

// per fine bucket: degree -> dinv; fused embedding: ag1 = bf16(emb[id]*dinv)
__global__ __launch_bounds__(BKTN) void k_degprep(const int* __restrict__ staging,
                                                  const int* __restrict__ bucket_off,
                                                  const int* __restrict__ x_ids,
                                                  const float* __restrict__ emb,
                                                  int N,
                                                  float* __restrict__ dinv,
                                                  unsigned short* __restrict__ ag1) {
  __shared__ int cnt[BKTN];
  int tid = threadIdx.x, b = blockIdx.x;
  int beg = bucket_off[b], end = bucket_off[b + 1];
  cnt[tid] = 0;
  __syncthreads();
  for (int i = beg + tid; i < end; i += BKTN)
    atomicAdd(&cnt[staging[i] & (BKTN - 1)], 1);
  __syncthreads();
  int node = (b << BSH) + tid;
  if (node >= N) return;
  float d = rsqrtf((float)(cnt[tid] + 1));  // +1 self-loop
  dinv[node] = d;
  const float* er = emb + (size_t)x_ids[node] * 16;
  float4 e0 = *(const float4*)(er);
  float4 e1 = *(const float4*)(er + 4);
  float4 e2 = *(const float4*)(er + 8);
  float4 e3 = *(const float4*)(er + 12);
  uint4 o0, o1;
  o0.x = pk(e0.x * d, e0.y * d); o0.y = pk(e0.z * d, e0.w * d);
  o0.z = pk(e1.x * d, e1.y * d); o0.w = pk(e1.z * d, e1.w * d);
  o1.x = pk(e2.x * d, e2.y * d); o1.y = pk(e2.z * d, e2.w * d);
  o1.z = pk(e3.x * d, e3.y * d); o1.w = pk(e3.z * d, e3.w * d);
  *(uint4*)(ag1 + (size_t)node * 16) = o0;
  *(uint4*)(ag1 + (size_t)node * 16 + 8) = o1;
}

// layer 1: LDS CSR rebuild + register aggregation + fused GEMV/ReLU.
// 512 threads: 2 lanes/node (half = 8 features, uint4 gathers).
__global__ __launch_bounds__(512) void k_fuse1(const unsigned short* __restrict__ ag1,
                                               const int* __restrict__ staging,
                                               const int* __restrict__ bucket_off,
                                               const float* __restrict__ dinv,
                                               const float* __restrict__ W1,
                                               const float* __restrict__ b1, int N,
                                               unsigned short* __restrict__ y1g) {
  __shared__ int list[CAP];
  __shared__ int cnt[BKTN], sc[BKTN], lcur[BKTN];
  __shared__ float W[512];
  __shared__ float bb[32];
  int tid = threadIdx.x, b = blockIdx.x;
  W[tid] = W1[tid];
  if (tid < 32) bb[tid] = b1[tid];
  int nloc = tid >> 1, half = tid & 1;
  int node = (b << BSH) + nloc;
  float acc[8];
  if (node < N) {
    uint4 v = *(const uint4*)(ag1 + (size_t)node * 16 + half * 8);
    acc[0] = bf2f(v.x & 0xFFFF); acc[1] = bf2f(v.x >> 16);
    acc[2] = bf2f(v.y & 0xFFFF); acc[3] = bf2f(v.y >> 16);
    acc[4] = bf2f(v.z & 0xFFFF); acc[5] = bf2f(v.z >> 16);
    acc[6] = bf2f(v.w & 0xFFFF); acc[7] = bf2f(v.w >> 16);
  } else {
#pragma unroll
    for (int k = 0; k < 8; ++k) acc[k] = 0.f;
  }
  int beg = bucket_off[b], end = bucket_off[b + 1];
  for (int cbeg = beg; cbeg < end; cbeg += CAP) {
    int cend = min(end, cbeg + CAP);
    if (tid < BKTN) cnt[tid] = 0;
    __syncthreads();
    for (int i = cbeg + tid; i < cend; i += 512)
      atomicAdd(&cnt[staging[i] & (BKTN - 1)], 1);
    __syncthreads();
    if (tid < BKTN) sc[tid] = cnt[tid];
    __syncthreads();
    for (int o = 1; o < BKTN; o <<= 1) {
      int u = (tid < BKTN && tid >= o) ? sc[tid - o] : 0;
      __syncthreads();
      if (tid < BKTN) sc[tid] += u;
      __syncthreads();
    }
    if (tid < BKTN) {
      int st = sc[tid] - cnt[tid];
      sc[tid] = st;
      lcur[tid] = st;
    }
    __syncthreads();
    for (int i = cbeg + tid; i < cend; i += 512) {
      int p = staging[i];
      int pos = atomicAdd(&lcur[p & (BKTN - 1)], 1);
      list[pos] = p >> BSH;
    }
    __syncthreads();
    if (node < N) {
      int st = sc[nloc], dg = cnt[nloc];
      for (int j = 0; j < dg; ++j) {
        int r = list[st + j];
        uint4 v = *(const uint4*)(ag1 + (size_t)r * 16 + half * 8);
        acc[0] += bf2f(v.x & 0xFFFF); acc[1] += bf2f(v.x >> 16);
        acc[2] += bf2f(v.y & 0xFFFF); acc[3] += bf2f(v.y >> 16);
        acc[4] += bf2f(v.z & 0xFFFF); acc[5] += bf2f(v.z >> 16);
        acc[6] += bf2f(v.w & 0xFFFF); acc[7] += bf2f(v.w >> 16);
      }
    }
    __syncthreads();
  }
  if (node >= N) return;
  float d = dinv[node];
  float sx[8], xo[8];
#pragma unroll
  for (int k = 0; k < 8; ++k) sx[k] = acc[k] * d;
#pragma unroll
  for (int k = 0; k < 8; ++k) xo[k] = __shfl_xor(sx[k], 1);
  float x[16];
  if (half == 0) {
#pragma unroll
    for (int k = 0; k < 8; ++k) { x[k] = sx[k]; x[8 + k] = xo[k]; }
  } else {
#pragma unroll
    for (int k = 0; k < 8; ++k) { x[k] = xo[k]; x[8 + k] = sx[k]; }
  }
  int j0 = half * 16;
  float a[16];
#pragma unroll
  for (int j = 0; j < 16; ++j) a[j] = bb[j0 + j];
#pragma unroll
  for (int k = 0; k < 16; ++k) {
    float xv = x[k];
#pragma unroll
    for (int j = 0; j < 16; ++j) a[j] += xv * W[k * 32 + j0 + j];
  }
#pragma unroll
  for (int j = 0; j < 16; ++j) a[j] = fmaxf(a[j], 0.f) * d;
  uint4 o0 = {pk(a[0], a[1]), pk(a[2], a[3]), pk(a[4], a[5]), pk(a[6], a[7])};
  uint4 o1 = {pk(a[8], a[9]), pk(a[10], a[11]), pk(a[12], a[13]), pk(a[14], a[15])};
  unsigned short* yp = y1g + (size_t)half * N * 16 + (size_t)node * 16;
  *(uint4*)(yp) = o0;
  *(uint4*)(yp + 8) = o1;
}

// layer 2, ONE 16-feat plane: LDS CSR rebuild + register aggregation +
// fused sorted-batch graph pooling -> atomicAdd P[G][32] at pofs
__global__ __launch_bounds__(512) void k_fuse2(const unsigned short* __restrict__ y1p,
                                               const int* __restrict__ staging,
                                               const int* __restrict__ bucket_off,
                                               const float* __restrict__ dinv,
                                               const int* __restrict__ batch, int N,
                                               int pofs, float* __restrict__ P) {
  __shared__ int list[CAP];
  __shared__ int cnt[BKTN], sc[BKTN], lcur[BKTN];
  __shared__ float pool[8 * 16];
  int tid = threadIdx.x, b = blockIdx.x;
  int nloc = tid >> 1, half = tid & 1;
  int node = (b << BSH) + nloc;
  float acc[8];
  if (node < N) {
    uint4 v = *(const uint4*)(y1p + (size_t)node * 16 + half * 8);
    acc[0] = bf2f(v.x & 0xFFFF); acc[1] = bf2f(v.x >> 16);
    acc[2] = bf2f(v.y & 0xFFFF); acc[3] = bf2f(v.y >> 16);
    acc[4] = bf2f(v.z & 0xFFFF); acc[5] = bf2f(v.z >> 16);
    acc[6] = bf2f(v.w & 0xFFFF); acc[7] = bf2f(v.w >> 16);
  } else {
#pragma unroll
    for (int k = 0; k < 8; ++k) acc[k] = 0.f;
  }
  int beg = bucket_off[b], end = bucket_off[b + 1];
  for (int cbeg = beg; cbeg < end; cbeg += CAP) {
    int cend = min(end, cbeg + CAP);
    if (tid < BKTN) cnt[tid] = 0;
    __syncthreads();
    for (int i = cbeg + tid; i < cend; i += 512)
      atomicAdd(&cnt[staging[i] & (BKTN - 1)], 1);
    __syncthreads();
    if (tid < BKTN) sc[tid] = cnt[tid];
    __syncthreads();
    for (int o = 1; o < BKTN; o <<= 1) {
      int u = (tid < BKTN && tid >= o) ? sc[tid - o] : 0;
      __syncthreads();
      if (tid < BKTN) sc[tid] += u;
      __syncthreads();
    }
    if (tid < BKTN) {
      int st = sc[tid] - cnt[tid];
      sc[tid] = st;
      lcur[tid] = st;
    }
    __syncthreads();
    for (int i = cbeg + tid; i < cend; i += 512) {
      int p = staging[i];
      int pos = atomicAdd(&lcur[p & (BKTN - 1)], 1);
      list[pos] = p >> BSH;
    }
    __syncthreads();
    if (node < N) {
      int st = sc[nloc], dg = cnt[nloc];
      for (int j = 0; j < dg; ++j) {
        int r = list[st + j];
        uint4 v = *(const uint4*)(y1p + (size_t)r * 16 + half * 8);
        acc[0] += bf2f(v.x & 0xFFFF); acc[1] += bf2f(v.x >> 16);
        acc[2] += bf2f(v.y & 0xFFFF); acc[3] += bf2f(v.y >> 16);
        acc[4] += bf2f(v.z & 0xFFFF); acc[5] += bf2f(v.z >> 16);
        acc[6] += bf2f(v.w & 0xFFFF); acc[7] += bf2f(v.w >> 16);
      }
    }
    __syncthreads();
  }
  int myg = -1;
  if (node < N) {
    float d = dinv[node];
#pragma unroll
    for (int k = 0; k < 8; ++k) acc[k] *= d;
    myg = batch[node];
  }
  int g0 = batch[b << BSH];
  int g1 = batch[min((b << BSH) + BKTN - 1, N - 1)];
  for (int clo = g0; clo <= g1; clo += 8) {
    for (int j = tid; j < 8 * 16; j += 512) pool[j] = 0.f;
    __syncthreads();
    if (myg >= clo && myg < clo + 8) {
      float* pp = pool + (myg - clo) * 16 + half * 8;
#pragma unroll
      for (int k = 0; k < 8; ++k) atomicAdd(pp + k, acc[k]);
    }
    __syncthreads();
    int ng = min(8, g1 - clo + 1);
    for (int j = tid; j < ng * 16; j += 512)
      atomicAdd(&P[(size_t)(clo + (j >> 4)) * 32 + pofs + (j & 15)], pool[j]);
    __syncthreads();
  }
}

// out[g] = P[g] @ W2 + cnt[g]*b2; cnt via binary search on sorted batch
__global__ __launch_bounds__(64) void k_final(const float* __restrict__ P,
                                              const int* __restrict__ batch, int N,
                                              const float* __restrict__ W2,
                                              const float* __restrict__ b2,
                                              float* __restrict__ out) {
  __shared__ float pr[32];
  __shared__ int se[2];
  int g = blockIdx.x, tid = threadIdx.x;
  if (tid < 2) {
    int v = g + tid;
    int lo = 0, hi = N;
    while (lo < hi) {
      int mid = (lo + hi) >> 1;
      if (batch[mid] < v) lo = mid + 1; else hi = mid;
    }
    se[tid] = lo;
  }
  if (tid < 32) pr[tid] = P[(size_t)g * 32 + tid];
  __syncthreads();
  if (tid < 41) {
    float o = (float)(se[1] - se[0]) * b2[tid];
#pragma unroll
    for (int k = 0; k < 32; ++k) o += pr[k] * W2[k * 41 + tid];
    out[(size_t)g * 41 + tid] = o;
  }
}

extern "C" void kernel_launch(void* const* d_in, const int* in_sizes, int n_in,
                              void* d_out, int out_size, void* d_ws, size_t ws_size,
                              hipStream_t stream) {
  const int* x_ids = (const int*)d_in[0];
  const int* edge_index = (const int*)d_in[1];
  const int* batch = (const int*)d_in[2];
  const float* emb = (const float*)d_in[3];
  const float* W1 = (const float*)d_in[4];
  const float* b1 = (const float*)d_in[5];
  const float* W2 = (const float*)d_in[6];
  const float* b2 = (const float*)d_in[7];
  float* out = (float*)d_out;

  const int N = in_sizes[0];
  const int E = in_sizes[1] / 2;
  const int G = out_size / 41;
  const int* row = edge_index;
  const int* col = edge_index + E;

  const int nbkt = (N + BKTN - 1) >> BSH;       // 391 fine buckets
  const int nblk = (E + EPB - 1) / EPB;         // 98 scatter blocks
  const int tot = nbkt * nblk;                  // ~38K
  const int nscan = (tot + 1023) >> 10;         // ~38

  char* ws = (char*)d_ws;
  size_t woff = 0;
  auto alloc = [&](size_t bytes) -> char* {
    char* p = ws + woff;
    woff += (bytes + 255) & ~(size_t)255;
    return p;
  };
  int* staging = (int*)alloc((size_t)E * 4);
  float* dinv = (float*)alloc((size_t)N * 4);
  unsigned short* ag1 = (unsigned short*)alloc((size_t)N * 16 * 2);
  unsigned short* y1g = (unsigned short*)alloc((size_t)N * 32 * 2);
  int* hist = (int*)alloc((size_t)tot * 4);
  int* off = (int*)alloc((size_t)tot * 4);
  int* bucket_off = (int*)alloc(((size_t)nbkt + 1) * 4);
  int* bsums = (int*)alloc((size_t)nscan * 4);
  float* P = (float*)alloc((size_t)G * 32 * 4);
  (void)ws_size; (void)n_in;

  hipMemsetAsync(P, 0, (size_t)G * 32 * 4, stream);

  k_hist<<<nblk, 1024, 0, stream>>>(col, E, nbkt, nblk, hist);
  k_scan_a<<<nscan, 1024, 0, stream>>>(hist, tot, off, bsums);
  k_scan_c<<<nscan, 1024, 0, stream>>>(tot, nblk, nbkt, E, nscan, bsums, off, bucket_off);
  k_scatter<<<nblk, 1024, 0, stream>>>(row, col, E, nbkt, nblk, off, staging);
  k_degprep<<<nbkt, BKTN, 0, stream>>>(staging, bucket_off, x_ids, emb, N, dinv, ag1);
  k_fuse1<<<nbkt, 512, 0, stream>>>(ag1, staging, bucket_off, dinv, W1, b1, N, y1g);
  k_fuse2<<<nbkt, 512, 0, stream>>>(y1g, staging, bucket_off, dinv, batch, N, 0, P);
  k_fuse2<<<nbkt, 512, 0, stream>>>(y1g + (size_t)N * 16, staging, bucket_off, dinv,
                                    batch, N, 16, P);
  k_final<<<G, 64, 0, stream>>>(P, batch, N, W2, b2, out);
}

// Round 11
// 236.633 us; speedup vs baseline: 1.2197x; 1.0782x over previous
//
#include <hip/hip_runtime.h>

// 2-layer GCN: one-pass counting sort to FINE buckets + LDS-local CSR +
// register aggregation, bf16 feature planes (R9 structure, verified 255us):
//   k_hist/k_scan: per-(fine bucket, scatter block) segment offsets
//   k_scatter: 200 blocks x 1024 thr, EPB=16384 -> 168B dense segments,
//              XCD-swizzled so memory-adjacent segments are written by
//              same-XCD blocks (R9: scatter was transaction-rate-bound on
//              98 CUs; R7: tiny segments shared lines across XCDs)
//   k_degprep: per fine bucket degree -> dinv; ag1 = bf16(emb[x_ids]*dinv)
//   k_fuse1:   per fine bucket LDS CSR rebuild; 2 lanes/node register gather
//              (uint4); shfl halves; fused 16->32 GEMV+ReLU -> y1g (2 planes)
//   k_fuse2 x2 (ONE PLANE each -- R8: merging planes doubled the gather set
//              past the 4MB per-XCD L2, FETCH 20->155MB): register gather +
//              fused sorted-batch pooling -> atomicAdd P[256][32]
//   k_final:   out[g] = P[g]@W2 + cnt[g]*b2
//
// Standing lessons: R1/R2 no scattered-4B global stores / no hot global
// atomics; R4 no single-block serial stages; R6 LDS-atomic edge-parallel
// starves the machine -> register accumulation only; R3/R8 every gather pass
// must fit one bf16 plane (3.2MB) in L2; R10 cooperative launch does not
// survive graph capture -> regular launches only.

constexpr int EPB = 16384;         // edges per hist/scatter block
constexpr int BSH = 8;             // 256 nodes per fine bucket
constexpr int BKTN = 1 << BSH;
constexpr int CAP = 10240;         // LDS edge-list capacity (chunked if over)

__device__ inline unsigned short f2bf(float x) {
  unsigned u = __float_as_uint(x);
  u += 0x7FFF + ((u >> 16) & 1);   // round-to-nearest-even
  return (unsigned short)(u >> 16);
}
__device__ inline float bf2f(unsigned short h) {
  return __uint_as_float((unsigned)h << 16);
}
__device__ inline unsigned pk(float a, float b) {
  return (unsigned)f2bf(a) | ((unsigned)f2bf(b) << 16);
}

// XCD swizzle: adjacent hist columns handled by same-XCD blocks (blk%8 heur.)
__device__ __forceinline__ int swz(int b, int nblkp) {
  return (b & 7) * (nblkp >> 3) + (b >> 3);
}

// per-block LDS histogram of fine col buckets
__global__ __launch_bounds__(1024) void k_hist(const int* __restrict__ col, int E,
                                               int nbkt, int nblkp,
                                               int* __restrict__ hist) {
  __shared__ int h[512];
  int tid = threadIdx.x;
  int blk = swz(blockIdx.x, nblkp);
  for (int i = tid; i < nbkt; i += 1024) h[i] = 0;
  __syncthreads();
  int e0 = blk * EPB, e1 = min(E, e0 + EPB);
  for (int e = e0 + tid; e < e1; e += 1024) atomicAdd(&h[col[e] >> BSH], 1);
  __syncthreads();
  for (int b = tid; b < nbkt; b += 1024) hist[b * nblkp + blk] = h[b];
}

// multi-block scan, stage 1: block-local exclusive scan + block sums
__global__ __launch_bounds__(1024) void k_scan_a(const int* __restrict__ hist, int tot,
                                                 int* __restrict__ off,
                                                 int* __restrict__ bsums) {
  __shared__ int sd[1024];
  int tid = threadIdx.x;
  int i = blockIdx.x * 1024 + tid;
  int v = (i < tot) ? hist[i] : 0;
  sd[tid] = v;
  __syncthreads();
  for (int o = 1; o < 1024; o <<= 1) {
    int u = (tid >= o) ? sd[tid - o] : 0;
    __syncthreads();
    sd[tid] += u;
    __syncthreads();
  }
  if (i < tot) off[i] = sd[tid] - v;  // block-local exclusive
  if (tid == 1023) bsums[blockIdx.x] = sd[tid];
}

// stage 2: add prefix of block sums (tree-reduced); derive bucket starts
__global__ __launch_bounds__(1024) void k_scan_c(int tot, int nblkp, int nbkt, int E,
                                                 int nscan,
                                                 const int* __restrict__ bsums,
                                                 int* __restrict__ off,
                                                 int* __restrict__ bucket_off) {
  __shared__ int sd[1024];
  int tid = threadIdx.x, b = blockIdx.x;
  sd[tid] = (tid < b && tid < nscan) ? bsums[tid] : 0;
  __syncthreads();
  for (int o = 512; o >= 1; o >>= 1) {
    if (tid < o) sd[tid] += sd[tid + o];
    __syncthreads();
  }
  int sbase = sd[0];
  int i = b * 1024 + tid;
  if (i < tot) {
    int v = off[i] + sbase;
    off[i] = v;
    if (i % nblkp == 0) bucket_off[i / nblkp] = v;
  }
  if (i == 0) bucket_off[nbkt] = E;
}

// scatter packed edges into fine-bucket-major segments (dense per block)
__global__ __launch_bounds__(1024) void k_scatter(const int* __restrict__ row,
                                                  const int* __restrict__ col, int E,
                                                  int nbkt, int nblkp,
                                                  const int* __restrict__ off,
                                                  int* __restrict__ staging) {
  __shared__ int base[512];
  __shared__ int cur[512];
  int tid = threadIdx.x;
  int blk = swz(blockIdx.x, nblkp);
  for (int b = tid; b < nbkt; b += 1024) {
    base[b] = off[b * nblkp + blk];
    cur[b] = 0;
  }
  __syncthreads();
  int e0 = blk * EPB, e1 = min(E, e0 + EPB);
  for (int e = e0 + tid; e < e1; e += 1024) {
    int c = col[e];
    int b = c >> BSH;
    int rk = atomicAdd(&cur[b], 1);
    staging[base[b] + rk] = (row[e] << BSH) | (c & (BKTN - 1));
  }
}

// per fine bucket: degree -> dinv; fused embedding: ag1 = bf16(emb[id]*dinv)
__global__ __launch_bounds__(BKTN) void k_degprep(const int* __restrict__ staging,
                                                  const int* __restrict__ bucket_off,
                                                  const int* __restrict__ x_ids,
                                                  const float* __restrict__ emb,
                                                  int N,
                                                  float* __restrict__ dinv,
                                                  unsigned short* __restrict__ ag1) {
  __shared__ int cnt[BKTN];
  int tid = threadIdx.x, b = blockIdx.x;
  int beg = bucket_off[b], end = bucket_off[b + 1];
  cnt[tid] = 0;
  __syncthreads();
  for (int i = beg + tid; i < end; i += BKTN)
    atomicAdd(&cnt[staging[i] & (BKTN - 1)], 1);
  __syncthreads();
  int node = (b << BSH) + tid;
  if (node >= N) return;
  float d = rsqrtf((float)(cnt[tid] + 1));  // +1 self-loop
  dinv[node] = d;
  const float* er = emb + (size_t)x_ids[node] * 16;
  float4 e0 = *(const float4*)(er);
  float4 e1 = *(const float4*)(er + 4);
  float4 e2 = *(const float4*)(er + 8);
  float4 e3 = *(const float4*)(er + 12);
  uint4 o0, o1;
  o0.x = pk(e0.x * d, e0.y * d); o0.y = pk(e0.z * d, e0.w * d);
  o0.z = pk(e1.x * d, e1.y * d); o0.w = pk(e1.z * d, e1.w * d);
  o1.x = pk(e2.x * d, e2.y * d); o1.y = pk(e2.z * d, e2.w * d);
  o1.z = pk(e3.x * d, e3.y * d); o1.w = pk(e3.z * d, e3.w * d);
  *(uint4*)(ag1 + (size_t)node * 16) = o0;
  *(uint4*)(ag1 + (size_t)node * 16 + 8) = o1;
}

// layer 1: LDS CSR rebuild + register aggregation + fused GEMV/ReLU.
// 512 threads: 2 lanes/node (half = 8 features, uint4 gathers).
__global__ __launch_bounds__(512) void k_fuse1(const unsigned short* __restrict__ ag1,
                                               const int* __restrict__ staging,
                                               const int* __restrict__ bucket_off,
                                               const float* __restrict__ dinv,
                                               const float* __restrict__ W1,
                                               const float* __restrict__ b1, int N,
                                               unsigned short* __restrict__ y1g) {
  __shared__ int list[CAP];
  __shared__ int cnt[BKTN], sc[BKTN], lcur[BKTN];
  __shared__ float W[512];
  __shared__ float bb[32];
  int tid = threadIdx.x, b = blockIdx.x;
  W[tid] = W1[tid];
  if (tid < 32) bb[tid] = b1[tid];
  int nloc = tid >> 1, half = tid & 1;
  int node = (b << BSH) + nloc;
  float acc[8];
  if (node < N) {
    uint4 v = *(const uint4*)(ag1 + (size_t)node * 16 + half * 8);
    acc[0] = bf2f(v.x & 0xFFFF); acc[1] = bf2f(v.x >> 16);
    acc[2] = bf2f(v.y & 0xFFFF); acc[3] = bf2f(v.y >> 16);
    acc[4] = bf2f(v.z & 0xFFFF); acc[5] = bf2f(v.z >> 16);
    acc[6] = bf2f(v.w & 0xFFFF); acc[7] = bf2f(v.w >> 16);
  } else {
#pragma unroll
    for (int k = 0; k < 8; ++k) acc[k] = 0.f;
  }
  int beg = bucket_off[b], end = bucket_off[b + 1];
  for (int cbeg = beg; cbeg < end; cbeg += CAP) {
    int cend = min(end, cbeg + CAP);
    if (tid < BKTN) cnt[tid] = 0;
    __syncthreads();
    for (int i = cbeg + tid; i < cend; i += 512)
      atomicAdd(&cnt[staging[i] & (BKTN - 1)], 1);
    __syncthreads();
    if (tid < BKTN) sc[tid] = cnt[tid];
    __syncthreads();
    for (int o = 1; o < BKTN; o <<= 1) {
      int u = (tid < BKTN && tid >= o) ? sc[tid - o] : 0;
      __syncthreads();
      if (tid < BKTN) sc[tid] += u;
      __syncthreads();
    }
    if (tid < BKTN) {
      int st = sc[tid] - cnt[tid];
      sc[tid] = st;
      lcur[tid] = st;
    }
    __syncthreads();
    for (int i = cbeg + tid; i < cend; i += 512) {
      int p = staging[i];
      int pos = atomicAdd(&lcur[p & (BKTN - 1)], 1);
      list[pos] = p >> BSH;
    }
    __syncthreads();
    if (node < N) {
      int st = sc[nloc], dg = cnt[nloc];
      for (int j = 0; j < dg; ++j) {
        int r = list[st + j];
        uint4 v = *(const uint4*)(ag1 + (size_t)r * 16 + half * 8);
        acc[0] += bf2f(v.x & 0xFFFF); acc[1] += bf2f(v.x >> 16);
        acc[2] += bf2f(v.y & 0xFFFF); acc[3] += bf2f(v.y >> 16);
        acc[4] += bf2f(v.z & 0xFFFF); acc[5] += bf2f(v.z >> 16);
        acc[6] += bf2f(v.w & 0xFFFF); acc[7] += bf2f(v.w >> 16);
      }
    }
    __syncthreads();
  }
  if (node >= N) return;
  float d = dinv[node];
  float sx[8], xo[8];
#pragma unroll
  for (int k = 0; k < 8; ++k) sx[k] = acc[k] * d;
#pragma unroll
  for (int k = 0; k < 8; ++k) xo[k] = __shfl_xor(sx[k], 1);
  float x[16];
  if (half == 0) {
#pragma unroll
    for (int k = 0; k < 8; ++k) { x[k] = sx[k]; x[8 + k] = xo[k]; }
  } else {
#pragma unroll
    for (int k = 0; k < 8; ++k) { x[k] = xo[k]; x[8 + k] = sx[k]; }
  }
  int j0 = half * 16;
  float a[16];
#pragma unroll
  for (int j = 0; j < 16; ++j) a[j] = bb[j0 + j];
#pragma unroll
  for (int k = 0; k < 16; ++k) {
    float xv = x[k];
#pragma unroll
    for (int j = 0; j < 16; ++j) a[j] += xv * W[k * 32 + j0 + j];
  }
#pragma unroll
  for (int j = 0; j < 16; ++j) a[j] = fmaxf(a[j], 0.f) * d;
  uint4 o0 = {pk(a[0], a[1]), pk(a[2], a[3]), pk(a[4], a[5]), pk(a[6], a[7])};
  uint4 o1 = {pk(a[8], a[9]), pk(a[10], a[11]), pk(a[12], a[13]), pk(a[14], a[15])};
  unsigned short* yp = y1g + (size_t)half * N * 16 + (size_t)node * 16;
  *(uint4*)(yp) = o0;
  *(uint4*)(yp + 8) = o1;
}

// layer 2, ONE 16-feat plane: LDS CSR rebuild + register aggregation +
// fused sorted-batch graph pooling -> atomicAdd P[G][32] at pofs
__global__ __launch_bounds__(512) void k_fuse2(const unsigned short* __restrict__ y1p,
                                               const int* __restrict__ staging,
                                               const int* __restrict__ bucket_off,
                                               const float* __restrict__ dinv,
                                               const int* __restrict__ batch, int N,
                                               int pofs, float* __restrict__ P) {
  __shared__ int list[CAP];
  __shared__ int cnt[BKTN], sc[BKTN], lcur[BKTN];
  __shared__ float pool[8 * 16];
  int tid = threadIdx.x, b = blockIdx.x;
  int nloc = tid >> 1, half = tid & 1;
  int node = (b << BSH) + nloc;
  float acc[8];
  if (node < N) {
    uint4 v = *(const uint4*)(y1p + (size_t)node * 16 + half * 8);
    acc[0] = bf2f(v.x & 0xFFFF); acc[1] = bf2f(v.x >> 16);
    acc[2] = bf2f(v.y & 0xFFFF); acc[3] = bf2f(v.y >> 16);
    acc[4] = bf2f(v.z & 0xFFFF); acc[5] = bf2f(v.z >> 16);
    acc[6] = bf2f(v.w & 0xFFFF); acc[7] = bf2f(v.w >> 16);
  } else {
#pragma unroll
    for (int k = 0; k < 8; ++k) acc[k] = 0.f;
  }
  int beg = bucket_off[b], end = bucket_off[b + 1];
  for (int cbeg = beg; cbeg < end; cbeg += CAP) {
    int cend = min(end, cbeg + CAP);
    if (tid < BKTN) cnt[tid] = 0;
    __syncthreads();
    for (int i = cbeg + tid; i < cend; i += 512)
      atomicAdd(&cnt[staging[i] & (BKTN - 1)], 1);
    __syncthreads();
    if (tid < BKTN) sc[tid] = cnt[tid];
    __syncthreads();
    for (int o = 1; o < BKTN; o <<= 1) {
      int u = (tid < BKTN && tid >= o) ? sc[tid - o] : 0;
      __syncthreads();
      if (tid < BKTN) sc[tid] += u;
      __syncthreads();
    }
    if (tid < BKTN) {
      int st = sc[tid] - cnt[tid];
      sc[tid] = st;
      lcur[tid] = st;
    }
    __syncthreads();
    for (int i = cbeg + tid; i < cend; i += 512) {
      int p = staging[i];
      int pos = atomicAdd(&lcur[p & (BKTN - 1)], 1);
      list[pos] = p >> BSH;
    }
    __syncthreads();
    if (node < N) {
      int st = sc[nloc], dg = cnt[nloc];
      for (int j = 0; j < dg; ++j) {
        int r = list[st + j];
        uint4 v = *(const uint4*)(y1p + (size_t)r * 16 + half * 8);
        acc[0] += bf2f(v.x & 0xFFFF); acc[1] += bf2f(v.x >> 16);
        acc[2] += bf2f(v.y & 0xFFFF); acc[3] += bf2f(v.y >> 16);
        acc[4] += bf2f(v.z & 0xFFFF); acc[5] += bf2f(v.z >> 16);
        acc[6] += bf2f(v.w & 0xFFFF); acc[7] += bf2f(v.w >> 16);
      }
    }
    __syncthreads();
  }
  int myg = -1;
  if (node < N) {
    float d = dinv[node];
#pragma unroll
    for (int k = 0; k < 8; ++k) acc[k] *= d;
    myg = batch[node];
  }
  int g0 = batch[b << BSH];
  int g1 = batch[min((b << BSH) + BKTN - 1, N - 1)];
  for (int clo = g0; clo <= g1; clo += 8) {
    for (int j = tid; j < 8 * 16; j += 512) pool[j] = 0.f;
    __syncthreads();
    if (myg >= clo && myg < clo + 8) {
      float* pp = pool + (myg - clo) * 16 + half * 8;
#pragma unroll
      for (int k = 0; k < 8; ++k) atomicAdd(pp + k, acc[k]);
    }
    __syncthreads();
    int ng = min(8, g1 - clo + 1);
    for (int j = tid; j < ng * 16; j += 512)
      atomicAdd(&P[(size_t)(clo + (j >> 4)) * 32 + pofs + (j & 15)], pool[j]);
    __syncthreads();
  }
}

// out[g] = P[g] @ W2 + cnt[g]*b2; cnt via binary search on sorted batch
__global__ __launch_bounds__(64) void k_final(const float* __restrict__ P,
                                              const int* __restrict__ batch, int N,
                                              const float* __restrict__ W2,
                                              const float* __restrict__ b2,
                                              float* __restrict__ out) {
  __shared__ float pr[32];
  __shared__ int se[2];
  int g = blockIdx.x, tid = threadIdx.x;
  if (tid < 2) {
    int v = g + tid;
    int lo = 0, hi = N;
    while (lo < hi) {
      int mid = (lo + hi) >> 1;
      if (batch[mid] < v) lo = mid + 1; else hi = mid;
    }
    se[tid] = lo;
  }
  if (tid < 32) pr[tid] = P[(size_t)g * 32 + tid];
  __syncthreads();
  if (tid < 41) {
    float o = (float)(se[1] - se[0]) * b2[tid];
#pragma unroll
    for (int k = 0; k < 32; ++k) o += pr[k] * W2[k * 41 + tid];
    out[(size_t)g * 41 + tid] = o;
  }
}

extern "C" void kernel_launch(void* const* d_in, const int* in_sizes, int n_in,
                              void* d_out, int out_size, void* d_ws, size_t ws_size,
                              hipStream_t stream) {
  const int* x_ids = (const int*)d_in[0];
  const int* edge_index = (const int*)d_in[1];
  const int* batch = (const int*)d_in[2];
  const float* emb = (const float*)d_in[3];
  const float* W1 = (const float*)d_in[4];
  const float* b1 = (const float*)d_in[5];
  const float* W2 = (const float*)d_in[6];
  const float* b2 = (const float*)d_in[7];
  float* out = (float*)d_out;

  const int N = in_sizes[0];
  const int E = in_sizes[1] / 2;
  const int G = out_size / 41;
  const int* row = edge_index;
  const int* col = edge_index + E;

  const int nbkt = (N + BKTN - 1) >> BSH;       // 391 fine buckets
  int nblk = (E + EPB - 1) / EPB;               // 196
  const int nblkp = (nblk + 7) & ~7;            // 200 (pad for XCD swizzle)
  const int tot = nbkt * nblkp;                 // ~78K
  const int nscan = (tot + 1023) >> 10;         // ~77

  char* ws = (char*)d_ws;
  size_t woff = 0;
  auto alloc = [&](size_t bytes) -> char* {
    char* p = ws + woff;
    woff += (bytes + 255) & ~(size_t)255;
    return p;
  };
  int* staging = (int*)alloc((size_t)E * 4);
  float* dinv = (float*)alloc((size_t)N * 4);
  unsigned short* ag1 = (unsigned short*)alloc((size_t)N * 16 * 2);
  unsigned short* y1g = (unsigned short*)alloc((size_t)N * 32 * 2);
  int* hist = (int*)alloc((size_t)tot * 4);
  int* off = (int*)alloc((size_t)tot * 4);
  int* bucket_off = (int*)alloc(((size_t)nbkt + 1) * 4);
  int* bsums = (int*)alloc((size_t)nscan * 4);
  float* P = (float*)alloc((size_t)G * 32 * 4);
  (void)ws_size; (void)n_in;

  hipMemsetAsync(P, 0, (size_t)G * 32 * 4, stream);

  k_hist<<<nblkp, 1024, 0, stream>>>(col, E, nbkt, nblkp, hist);
  k_scan_a<<<nscan, 1024, 0, stream>>>(hist, tot, off, bsums);
  k_scan_c<<<nscan, 1024, 0, stream>>>(tot, nblkp, nbkt, E, nscan, bsums, off, bucket_off);
  k_scatter<<<nblkp, 1024, 0, stream>>>(row, col, E, nbkt, nblkp, off, staging);
  k_degprep<<<nbkt, BKTN, 0, stream>>>(staging, bucket_off, x_ids, emb, N, dinv, ag1);
  k_fuse1<<<nbkt, 512, 0, stream>>>(ag1, staging, bucket_off, dinv, W1, b1, N, y1g);
  k_fuse2<<<nbkt, 512, 0, stream>>>(y1g, staging, bucket_off, dinv, batch, N, 0, P);
  k_fuse2<<<nbkt, 512, 0, stream>>>(y1g + (size_t)N * 16, staging, bucket_off, dinv,
                                    batch, N, 16, P);
  k_final<<<G, 64, 0, stream>>>(P, batch, N, W2, b2, out);
}